// Round 6
// baseline (53.459 us; speedup 1.0000x reference)
//
#include <hip/hip_runtime.h>
#include <math.h>

// DTLN part-2 in TWO kernels (one boundary = the only all-to-all sync).
// K1: enc = enc_W @ y1 (split across 64 blocks).
// K2: 32 blocks x 1024 thr; each block redundantly runs LN -> z1 -> h1 ->
//     z2 -> h2 -> mask (1.4MB weights/block, L2-shared within XCD), then
//     the 1024 decoder rows are split 32/block. No atomics, no barriers.

#define FRAME 1024
#define ENC 256
#define HID 128

__device__ __forceinline__ float sigmoidf_(float x) { return 1.0f / (1.0f + __expf(-x)); }
__device__ __forceinline__ float tanhf_(float x) { return 2.0f * sigmoidf_(2.0f * x) - 1.0f; }

__device__ __forceinline__ float wred(float v) {
#pragma unroll
    for (int o = 32; o > 0; o >>= 1) v += __shfl_xor(v, o);
    return v;
}

// ---- K1: enc rows (256 x K=1024), 64 blocks, 1 row/wave ----
__global__ __launch_bounds__(256) void k_enc(const float* __restrict__ enc_W,
                                             const float* __restrict__ y1,
                                             float* __restrict__ enc_g) {
    const int t = threadIdx.x, lane = t & 63, w = t >> 6;
    const int r = blockIdx.x * 4 + w;
    const float4* W4 = reinterpret_cast<const float4*>(enc_W + r * FRAME);
    const float4* Y4 = reinterpret_cast<const float4*>(y1);
    float s = 0.f;
#pragma unroll
    for (int j = 0; j < 4; ++j) {
        const float4 a = W4[j * 64 + lane];
        const float4 b = Y4[j * 64 + lane];
        s += a.x * b.x + a.y * b.y + a.z * b.z + a.w * b.w;
    }
    s = wred(s);
    if (lane == 0) enc_g[r] = s;
}

// ---- K2: everything else. 32 blocks x 1024 threads ----
__global__ __launch_bounds__(1024, 1) void k_rest(
    const float* __restrict__ enc_g,
    const float* __restrict__ h1_in, const float* __restrict__ c1_in,
    const float* __restrict__ h2_in, const float* __restrict__ c2_in,
    const float* __restrict__ gamma, const float* __restrict__ beta,
    const float* __restrict__ Wih1, const float* __restrict__ Whh1,
    const float* __restrict__ bih1, const float* __restrict__ bhh1,
    const float* __restrict__ Wih2, const float* __restrict__ Whh2,
    const float* __restrict__ bih2, const float* __restrict__ bhh2,
    const float* __restrict__ dense_W, const float* __restrict__ dense_b,
    const float* __restrict__ dec_W, float* __restrict__ out)
{
    const int t = threadIdx.x, lane = t & 63, w = t >> 6, bid = blockIdx.x;
    const int sub = lane >> 2, q = lane & 3;

    __shared__ __align__(16) float encL[ENC];
    __shared__ __align__(16) float encN[ENC];
    __shared__ __align__(16) float h1s[HID];
    __shared__ __align__(16) float h2s[HID];
    __shared__ __align__(16) float z[4 * HID];
    __shared__ __align__(16) float est[ENC];
    __shared__ __align__(16) float zb1[4 * HID];
    __shared__ __align__(16) float zb2[4 * HID];
    __shared__ __align__(16) float dbs[ENC];
    __shared__ float red[8];

    // ---- A: stage small vectors ----
    if (t < ENC) { encL[t] = enc_g[t]; dbs[t] = dense_b[t]; }
    if (t < HID) { h1s[t] = h1_in[t]; h2s[t] = h2_in[t]; }
    if (t < 4 * HID) { zb1[t] = bih1[t] + bhh1[t]; zb2[t] = bih2[t] + bhh2[t]; }
    __syncthreads();

    // ---- B: LN (waves 0..3 reduce 64 each) ----
    if (t < ENC) {
        const float e = encL[t];
        const float s1 = wred(e);
        const float s2 = wred(e * e);
        if (lane == 0) { red[w] = s1; red[4 + w] = s2; }
    }
    __syncthreads();
    {
        const float mean = (red[0] + red[1] + red[2] + red[3]) * (1.f / ENC);
        const float var  = (red[4] + red[5] + red[6] + red[7]) * (1.f / ENC) - mean * mean;
        const float inv  = rsqrtf(var + 1e-7f);
        if (t < ENC) encN[t] = (encL[t] - mean) * inv * gamma[t] + beta[t];
    }
    __syncthreads();

    // ---- C: z1 (512 rows, K=256+128); 32 rows/wave, 4 lanes/row ----
    {
        const float4* xa = reinterpret_cast<const float4*>(encN) + q * 16;
        const float4* xb = reinterpret_cast<const float4*>(h1s) + q * 8;
#pragma unroll
        for (int pass = 0; pass < 2; ++pass) {
            const int r = w * 32 + pass * 16 + sub;
            const float4* Wa = reinterpret_cast<const float4*>(Wih1 + r * ENC) + q * 16;
            const float4* Wb = reinterpret_cast<const float4*>(Whh1 + r * HID) + q * 8;
            float4 acc = {0.f, 0.f, 0.f, 0.f};
#pragma unroll 8
            for (int j = 0; j < 16; ++j) {
                const float4 a = Wa[j], b = xa[j];
                acc.x += a.x * b.x; acc.y += a.y * b.y;
                acc.z += a.z * b.z; acc.w += a.w * b.w;
            }
#pragma unroll 8
            for (int j = 0; j < 8; ++j) {
                const float4 a = Wb[j], b = xb[j];
                acc.x += a.x * b.x; acc.y += a.y * b.y;
                acc.z += a.z * b.z; acc.w += a.w * b.w;
            }
            float s = acc.x + acc.y + acc.z + acc.w;
            s += __shfl_xor(s, 1); s += __shfl_xor(s, 2);
            if (q == 0) z[r] = s + zb1[r];
        }
    }
    __syncthreads();

    // ---- D: gates1 -> h1 (z consumed, h1s overwritten) ----
    if (t < HID) {
        const float i = sigmoidf_(z[t]);
        const float f = sigmoidf_(z[HID + t]);
        const float g = tanhf_(z[2 * HID + t]);
        const float o = sigmoidf_(z[3 * HID + t]);
        const float c = f * c1_in[t] + i * g;
        const float h = o * tanhf_(c);
        h1s[t] = h;
        if (bid == 0) { out[FRAME + t] = h; out[FRAME + HID + t] = c; }
    }
    __syncthreads();

    // ---- E: z2 (512 rows, K=128+128) ----
    {
        const float4* xa = reinterpret_cast<const float4*>(h1s) + q * 8;
        const float4* xb = reinterpret_cast<const float4*>(h2s) + q * 8;
#pragma unroll
        for (int pass = 0; pass < 2; ++pass) {
            const int r = w * 32 + pass * 16 + sub;
            const float4* Wa = reinterpret_cast<const float4*>(Wih2 + r * HID) + q * 8;
            const float4* Wb = reinterpret_cast<const float4*>(Whh2 + r * HID) + q * 8;
            float4 acc = {0.f, 0.f, 0.f, 0.f};
#pragma unroll 8
            for (int j = 0; j < 8; ++j) {
                const float4 a = Wa[j], b = xa[j];
                const float4 a2 = Wb[j], b2 = xb[j];
                acc.x += a.x * b.x + a2.x * b2.x;
                acc.y += a.y * b.y + a2.y * b2.y;
                acc.z += a.z * b.z + a2.z * b2.z;
                acc.w += a.w * b.w + a2.w * b2.w;
            }
            float s = acc.x + acc.y + acc.z + acc.w;
            s += __shfl_xor(s, 1); s += __shfl_xor(s, 2);
            if (q == 0) z[r] = s + zb2[r];
        }
    }
    __syncthreads();

    // ---- F: gates2 -> h2 ----
    if (t < HID) {
        const float i = sigmoidf_(z[t]);
        const float f = sigmoidf_(z[HID + t]);
        const float g = tanhf_(z[2 * HID + t]);
        const float o = sigmoidf_(z[3 * HID + t]);
        const float c = f * c2_in[t] + i * g;
        const float h = o * tanhf_(c);
        h2s[t] = h;
        if (bid == 0) { out[FRAME + 2 * HID + t] = h; out[FRAME + 3 * HID + t] = c; }
    }
    __syncthreads();

    // ---- G: mask/est (256 rows, K=128); 16 rows/wave ----
    {
        const int r = w * 16 + sub;
        const float4* Wd = reinterpret_cast<const float4*>(dense_W + r * HID) + q * 8;
        const float4* xd = reinterpret_cast<const float4*>(h2s) + q * 8;
        float4 acc = {0.f, 0.f, 0.f, 0.f};
#pragma unroll 8
        for (int j = 0; j < 8; ++j) {
            const float4 a = Wd[j], b = xd[j];
            acc.x += a.x * b.x; acc.y += a.y * b.y;
            acc.z += a.z * b.z; acc.w += a.w * b.w;
        }
        float s = acc.x + acc.y + acc.z + acc.w;
        s += __shfl_xor(s, 1); s += __shfl_xor(s, 2);
        if (q == 0) est[r] = sigmoidf_(s + dbs[r]) * encL[r];
    }
    __syncthreads();

    // ---- H: decoder rows split: 32/block, 2/wave, coalesced 1KB loads ----
    {
        const float4 xe = reinterpret_cast<const float4*>(est)[lane];
#pragma unroll
        for (int j = 0; j < 2; ++j) {
            const int r = bid * 32 + w * 2 + j;
            const float4 a = reinterpret_cast<const float4*>(dec_W + r * ENC)[lane];
            float s = a.x * xe.x + a.y * xe.y + a.z * xe.z + a.w * xe.w;
            s = wred(s);
            if (lane == 0) out[r] = s;
        }
    }
}

extern "C" void kernel_launch(void* const* d_in, const int* in_sizes, int n_in,
                              void* d_out, int out_size, void* d_ws, size_t ws_size,
                              hipStream_t stream) {
    const float* y1      = (const float*)d_in[0];
    const float* h1_in   = (const float*)d_in[1];
    const float* c1_in   = (const float*)d_in[2];
    const float* h2_in   = (const float*)d_in[3];
    const float* c2_in   = (const float*)d_in[4];
    const float* enc_W   = (const float*)d_in[5];
    const float* gamma   = (const float*)d_in[6];
    const float* beta    = (const float*)d_in[7];
    const float* Wih1    = (const float*)d_in[8];
    const float* Whh1    = (const float*)d_in[9];
    const float* bih1    = (const float*)d_in[10];
    const float* bhh1    = (const float*)d_in[11];
    const float* Wih2    = (const float*)d_in[12];
    const float* Whh2    = (const float*)d_in[13];
    const float* bih2    = (const float*)d_in[14];
    const float* bhh2    = (const float*)d_in[15];
    const float* dense_W = (const float*)d_in[16];
    const float* dense_b = (const float*)d_in[17];
    const float* dec_W   = (const float*)d_in[18];

    float* out = (float*)d_out;
    float* enc_g = (float*)d_ws;

    k_enc<<<64, 256, 0, stream>>>(enc_W, y1, enc_g);
    k_rest<<<32, 1024, 0, stream>>>(enc_g, h1_in, c1_in, h2_in, c2_in,
                                    gamma, beta, Wih1, Whh1, bih1, bhh1,
                                    Wih2, Whh2, bih2, bhh2,
                                    dense_W, dense_b, dec_W, out);
}

// Round 7
// 19.081 us; speedup vs baseline: 2.8017x; 2.8017x over previous
//
#include <hip/hip_runtime.h>
#include <math.h>

// DTLN part-2, 5-kernel pipeline (4 boundaries = the dependency chain's minimum
// all-to-all syncs). Every weight cache line is fetched exactly once, by
// wave-contiguous row streams, spread across up to 256 CUs. Gate nonlinearities
// are finished inside the z-kernels via gate-row ownership (block b owns unit
// b's rows {b, b+128, b+256, b+384}), so no redundant prologues anywhere.

#define FRAME 1024
#define ENC 256
#define HID 128

__device__ __forceinline__ float sigmoidf_(float x) { return 1.0f / (1.0f + __expf(-x)); }
__device__ __forceinline__ float tanhf_(float x) { return 2.0f * sigmoidf_(2.0f * x) - 1.0f; }

__device__ __forceinline__ float wred(float v) {
#pragma unroll
    for (int o = 32; o > 0; o >>= 1) v += __shfl_xor(v, o);
    return v;  // all lanes
}

// ---- K1: enc = enc_W @ y1. 256 blocks, 1 row/block, 4 waves split K=1024 ----
__global__ __launch_bounds__(256) void k_enc(const float* __restrict__ enc_W,
                                             const float* __restrict__ y1,
                                             float* __restrict__ enc_g) {
    const int t = threadIdx.x, lane = t & 63, w = t >> 6, row = blockIdx.x;
    const float4 a = reinterpret_cast<const float4*>(enc_W + row * FRAME)[t];
    const float4 b = reinterpret_cast<const float4*>(y1)[t];
    float p = a.x * b.x + a.y * b.y + a.z * b.z + a.w * b.w;
    p = wred(p);
    __shared__ float red[4];
    if (lane == 0) red[w] = p;
    __syncthreads();
    if (t == 0) enc_g[row] = red[0] + red[1] + red[2] + red[3];
}

// ---- K2: LN (cheap, redundant) + z1 gate-rows of unit b + gates -> h1,c1 ----
// 128 blocks; wave w computes row r = b + 128*w (gate w of unit b), K=256+128.
__global__ __launch_bounds__(256) void k_z1(
    const float* __restrict__ enc_g, const float* __restrict__ gamma,
    const float* __restrict__ beta, const float* __restrict__ Wih1,
    const float* __restrict__ Whh1, const float* __restrict__ bih1,
    const float* __restrict__ bhh1, const float* __restrict__ h1_in,
    const float* __restrict__ c1_in, float* __restrict__ h1_g,
    float* __restrict__ out) {
    const int t = threadIdx.x, lane = t & 63, w = t >> 6, b = blockIdx.x;
    __shared__ __align__(16) float encN[ENC];
    __shared__ __align__(16) float hs[HID];
    __shared__ float red[8];
    __shared__ float zsh[4];

    const int r = b + HID * w;
    // issue weight loads first (no dependences)
    const float4 wa = reinterpret_cast<const float4*>(Wih1 + r * ENC)[lane];
    const float2 wb = reinterpret_cast<const float2*>(Whh1 + r * HID)[lane];
    const float bias = bih1[r] + bhh1[r];

    const float e = enc_g[t];
    const float s1 = wred(e);
    const float s2 = wred(e * e);
    if (lane == 0) { red[w] = s1; red[4 + w] = s2; }
    if (t < HID) hs[t] = h1_in[t];
    __syncthreads();
    const float mean = (red[0] + red[1] + red[2] + red[3]) * (1.f / ENC);
    const float var  = (red[4] + red[5] + red[6] + red[7]) * (1.f / ENC) - mean * mean;
    const float inv  = rsqrtf(var + 1e-7f);
    encN[t] = (e - mean) * inv * gamma[t] + beta[t];
    __syncthreads();

    const float4 xa = reinterpret_cast<const float4*>(encN)[lane];
    const float2 xb = reinterpret_cast<const float2*>(hs)[lane];
    float p = wa.x * xa.x + wa.y * xa.y + wa.z * xa.z + wa.w * xa.w
            + wb.x * xb.x + wb.y * xb.y;
    p = wred(p);
    if (lane == 0) zsh[w] = p + bias;
    __syncthreads();
    if (t == 0) {
        const float i = sigmoidf_(zsh[0]);
        const float f = sigmoidf_(zsh[1]);
        const float g = tanhf_(zsh[2]);
        const float o = sigmoidf_(zsh[3]);
        const float c = f * c1_in[b] + i * g;
        const float h = o * tanhf_(c);
        h1_g[b] = h;
        out[FRAME + b] = h;
        out[FRAME + HID + b] = c;
    }
}

// ---- K3: z2 gate-rows of unit b + gates -> h2,c2. 128 blocks, K=128+128 ----
__global__ __launch_bounds__(256) void k_z2(
    const float* __restrict__ h1_g, const float* __restrict__ h2_in,
    const float* __restrict__ Wih2, const float* __restrict__ Whh2,
    const float* __restrict__ bih2, const float* __restrict__ bhh2,
    const float* __restrict__ c2_in, float* __restrict__ h2_g,
    float* __restrict__ out) {
    const int t = threadIdx.x, lane = t & 63, w = t >> 6, b = blockIdx.x;
    __shared__ __align__(16) float hA[HID];
    __shared__ __align__(16) float hB[HID];
    __shared__ float zsh[4];

    const int r = b + HID * w;
    const float2 wa = reinterpret_cast<const float2*>(Wih2 + r * HID)[lane];
    const float2 wb = reinterpret_cast<const float2*>(Whh2 + r * HID)[lane];
    const float bias = bih2[r] + bhh2[r];

    if (t < HID) { hA[t] = h1_g[t]; hB[t] = h2_in[t]; }
    __syncthreads();
    const float2 xa = reinterpret_cast<const float2*>(hA)[lane];
    const float2 xb = reinterpret_cast<const float2*>(hB)[lane];
    float p = wa.x * xa.x + wa.y * xa.y + wb.x * xb.x + wb.y * xb.y;
    p = wred(p);
    if (lane == 0) zsh[w] = p + bias;
    __syncthreads();
    if (t == 0) {
        const float i = sigmoidf_(zsh[0]);
        const float f = sigmoidf_(zsh[1]);
        const float g = tanhf_(zsh[2]);
        const float o = sigmoidf_(zsh[3]);
        const float c = f * c2_in[b] + i * g;
        const float h = o * tanhf_(c);
        h2_g[b] = h;
        out[FRAME + 2 * HID + b] = h;
        out[FRAME + 3 * HID + b] = c;
    }
}

// ---- K4: est = sigmoid(dense_W@h2 + b) * enc. 64 blocks, 1 row/wave ----
__global__ __launch_bounds__(256) void k_mask(
    const float* __restrict__ h2_g, const float* __restrict__ dense_W,
    const float* __restrict__ dense_b, const float* __restrict__ enc_g,
    float* __restrict__ est_g) {
    const int t = threadIdx.x, lane = t & 63, w = t >> 6;
    __shared__ __align__(16) float hs[HID];
    const int r = blockIdx.x * 4 + w;
    const float2 wd = reinterpret_cast<const float2*>(dense_W + r * HID)[lane];
    if (t < HID) hs[t] = h2_g[t];
    __syncthreads();
    const float2 xd = reinterpret_cast<const float2*>(hs)[lane];
    float p = wd.x * xd.x + wd.y * xd.y;
    p = wred(p);
    if (lane == 0) est_g[r] = sigmoidf_(p + dense_b[r]) * enc_g[r];
}

// ---- K5: decoded = dec_W @ est. 256 blocks, 4 rows/block, 1 row/wave ----
__global__ __launch_bounds__(256) void k_dec(
    const float* __restrict__ dec_W, const float* __restrict__ est_g,
    float* __restrict__ out) {
    const int t = threadIdx.x, lane = t & 63, w = t >> 6;
    __shared__ __align__(16) float es[ENC];
    es[t] = est_g[t];
    __syncthreads();
    const int r = blockIdx.x * 4 + w;
    const float4 a = reinterpret_cast<const float4*>(dec_W + r * ENC)[lane];
    const float4 b = reinterpret_cast<const float4*>(es)[lane];
    float p = a.x * b.x + a.y * b.y + a.z * b.z + a.w * b.w;
    p = wred(p);
    if (lane == 0) out[r] = p;
}

extern "C" void kernel_launch(void* const* d_in, const int* in_sizes, int n_in,
                              void* d_out, int out_size, void* d_ws, size_t ws_size,
                              hipStream_t stream) {
    const float* y1      = (const float*)d_in[0];
    const float* h1_in   = (const float*)d_in[1];
    const float* c1_in   = (const float*)d_in[2];
    const float* h2_in   = (const float*)d_in[3];
    const float* c2_in   = (const float*)d_in[4];
    const float* enc_W   = (const float*)d_in[5];
    const float* gamma   = (const float*)d_in[6];
    const float* beta    = (const float*)d_in[7];
    const float* Wih1    = (const float*)d_in[8];
    const float* Whh1    = (const float*)d_in[9];
    const float* bih1    = (const float*)d_in[10];
    const float* bhh1    = (const float*)d_in[11];
    const float* Wih2    = (const float*)d_in[12];
    const float* Whh2    = (const float*)d_in[13];
    const float* bih2    = (const float*)d_in[14];
    const float* bhh2    = (const float*)d_in[15];
    const float* dense_W = (const float*)d_in[16];
    const float* dense_b = (const float*)d_in[17];
    const float* dec_W   = (const float*)d_in[18];

    float* out   = (float*)d_out;
    float* ws    = (float*)d_ws;
    float* enc_g = ws;          // 256
    float* h1_g  = ws + 256;    // 128
    float* h2_g  = ws + 384;    // 128
    float* est_g = ws + 512;    // 256

    k_enc <<<256, 256, 0, stream>>>(enc_W, y1, enc_g);
    k_z1  <<<128, 256, 0, stream>>>(enc_g, gamma, beta, Wih1, Whh1, bih1, bhh1,
                                    h1_in, c1_in, h1_g, out);
    k_z2  <<<128, 256, 0, stream>>>(h1_g, h2_in, Wih2, Whh2, bih2, bhh2,
                                    c2_in, h2_g, out);
    k_mask<<<64, 256, 0, stream>>>(h2_g, dense_W, dense_b, enc_g, est_g);
    k_dec <<<256, 256, 0, stream>>>(dec_W, est_g, out);
}